// Round 1
// baseline (2635.849 us; speedup 1.0000x reference)
//
#include <hip/hip_runtime.h>
#include <stdint.h>

// Problem constants
#define NSC 64
#define NVC 32
#define DIMF 160
#define LATD 128
#define HIDD 256
#define N_EDGES_K 300000
#define N_ACT_K 200000
#define NE_TILE 8

typedef unsigned short u16;

__device__ __forceinline__ float b2f(u16 x) {
    union { unsigned int u; float f; } v; v.u = ((unsigned int)x) << 16; return v.f;
}
__device__ __forceinline__ u16 f2b(float f) {
    union { unsigned int u; float f; } v; v.f = f;
    return (u16)((v.u + 0x7fffu + ((v.u >> 16) & 1u)) >> 16);
}

// F32=1: buffers are float32.  F32=0: buffers are bf16 (u16).
template<int F32>
__device__ __forceinline__ float ldx(const void* p, size_t i) {
    if (F32) return ((const float*)p)[i];
    return b2f(((const u16*)p)[i]);
}
template<int F32>
__device__ __forceinline__ void stx(void* p, size_t i, float v) {
    if (!(fabsf(v) < 1e30f)) v = 12345.0f;  // diagnostic sentinel: NaN/inf -> visible finite
    if (F32) ((float*)p)[i] = v;
    else     ((u16*)p)[i] = f2b(v);
}

__device__ __forceinline__ float wsum(float v) {
#pragma unroll
    for (int m = 32; m > 0; m >>= 1) v += __shfl_xor(v, m, 64);
    return v;
}
__device__ __forceinline__ float fsig(float x)  { return 1.f / (1.f + __expf(-x)); }
__device__ __forceinline__ float fsilu(float x) { return x / (1.f + __expf(-x)); }

// Normalize one DIM=160 row (64 scalars layernorm + 32 3-vectors rmsnorm), wave-cooperative.
// Vector part is written COMPONENT-PLANAR: dvp[c*96 + vbase + v]  (c=0..2, v=0..31)
// so that downstream GEMMs can read contiguous float4 along v.
template<int F32>
__device__ __forceinline__ void norm_row(const void* __restrict__ row, size_t off,
                                         const void* __restrict__ gs,
                                         const void* __restrict__ bs,
                                         const void* __restrict__ gv,
                                         float* ds, float* dvp, int vbase, int lane) {
    float s  = ldx<F32>(row, off + lane);
    float va = ldx<F32>(row, off + 64 + lane);
    float vb = (lane < 32) ? ldx<F32>(row, off + 128 + lane) : 0.f;
    float mu  = wsum(s) * (1.f / 64.f);
    float var = wsum(s * s) * (1.f / 64.f) - mu * mu;
    float n2  = wsum(va * va + vb * vb);
    float invs = rsqrtf(var + 1e-5f);
    float invv = rsqrtf(n2 * (1.f / 32.f) + 1e-5f);
    ds[lane] = (s - mu) * invs * ldx<F32>(gs, lane) + ldx<F32>(bs, lane);
    int v1 = lane / 3, c1 = lane - 3 * v1;                 // element 64+lane -> (v1,c1)
    dvp[c1 * 96 + vbase + v1] = va * invv * ldx<F32>(gv, v1);
    if (lane < 32) {
        int p = 64 + lane;                                  // element 128+lane -> (v2,c2)
        int v2 = p / 3, c2 = p - 3 * v2;
        dvp[c2 * 96 + vbase + v2] = vb * invv * ldx<F32>(gv, v2);
    }
}

// Detect input dtype: read 256 u16 from node_features (pure N(0,1) data).
__global__ void detect_kernel(const u16* __restrict__ probe, int* __restrict__ flag) {
    __shared__ int cnt;
    if (threadIdx.x == 0) cnt = 0;
    __syncthreads();
    u16 x = probe[threadIdx.x];
    int e = (x >> 7) & 0xFF;
    int sane = ((x & 0x7FFF) == 0) || (e >= 96 && e <= 143);
    atomicAdd(&cnt, sane);
    __syncthreads();
    if (threadIdx.x == 0) *flag = (cnt >= 240) ? 0 : 1;  // 0 = bf16, 1 = f32
}

template<int F32>
__global__ void copy_lat_kernel(const int* __restrict__ flag,
                                const uint4* __restrict__ in, uint4* __restrict__ out, int n) {
    if (*flag != F32) return;
    int i = blockIdx.x * blockDim.x + threadIdx.x;
    if (i < n) out[i] = in[i];
}

template<int F32>
__global__ __launch_bounds__(256, 3)
void edge_kernel(const int* __restrict__ flag,
                 const void* __restrict__ latents,
                 const void* __restrict__ nodef,
                 const void* __restrict__ onehot,
                 const void* __restrict__ edgef,
                 const void* __restrict__ esh,
                 const int* __restrict__ eidx,
                 const void* __restrict__ cutc,
                 const int* __restrict__ act,
                 const void* __restrict__ n_gs, const void* __restrict__ n_bs, const void* __restrict__ n_gv,
                 const void* __restrict__ e_gs, const void* __restrict__ e_bs, const void* __restrict__ e_gv,
                 const void* __restrict__ lg, const void* __restrict__ lb,
                 const void* __restrict__ Wa, const void* __restrict__ Wb,
                 const void* __restrict__ Wc, const void* __restrict__ Wd,
                 const void* __restrict__ Wps, const void* __restrict__ Wpv,
                 const void* __restrict__ Wedge, const void* __restrict__ Wl1,
                 const void* __restrict__ Wl2, const void* __restrict__ Wrs,
                 const void* __restrict__ Wrv,
                 void* __restrict__ out_edge, void* __restrict__ out_lat)
{
    if (*flag != F32) return;

    // arena: cols 0..191 = s_all, 192..287 = t2; later lat_in 0..231
    __shared__ float arena[NE_TILE][288];
    // vall: early = normalized v_all, COMPONENT-PLANAR [c*96 + v] (v: i 0..31, e 32..63, j 64..95)
    //       late  = raw edge features: s at [0..63], v planar at [64 + c*32 + v]
    __shared__ float vall[NE_TILE][288];
    __shared__ float osb [NE_TILE][96];
    __shared__ float latb[NE_TILE][128];
    __shared__ float latn[NE_TILE][128];
    __shared__ float wwb [NE_TILE][96];
    __shared__ float mspb[NE_TILE][64];
    __shared__ float mvpb[NE_TILE][96];    // planar [c*32 + o]
    __shared__ float msvb[NE_TILE][160];   // m_s (64) then m_v planar [64 + c*32 + w]
    __shared__ float hidb[NE_TILE][256];   // early: sWc (0..31) + vWd planar (32+c*32+o); late: hid
    __shared__ float shb [NE_TILE][4];
    __shared__ float ohib[NE_TILE][4];
    __shared__ float ohjb[NE_TILE][4];
    __shared__ float cutb[NE_TILE];
    __shared__ int   aib [NE_TILE];

    const int tid  = threadIdx.x;
    const int wid  = tid >> 6;
    const int lane = tid & 63;
    const int base = blockIdx.x * NE_TILE;

    // ---- Phase A: load + normalize (one wave per edge) ----
    for (int t = wid; t < NE_TILE; t += 4) {
        const int E = base + t;
        const int a = act[E];
        const int i = eidx[a];
        const int j = eidx[N_EDGES_K + a];
        norm_row<F32>(nodef, (size_t)i * DIMF, n_gs, n_bs, n_gv, &arena[t][0],   &vall[t][0], 0,  lane);
        norm_row<F32>(edgef, (size_t)E * DIMF, e_gs, e_bs, e_gv, &arena[t][64],  &vall[t][0], 32, lane);
        norm_row<F32>(nodef, (size_t)j * DIMF, n_gs, n_bs, n_gv, &arena[t][128], &vall[t][0], 64, lane);
        float x0 = ldx<F32>(latents, (size_t)a * LATD + lane);
        float x1 = ldx<F32>(latents, (size_t)a * LATD + 64 + lane);
        float mu  = wsum(x0 + x1) * (1.f / 128.f);
        float var = wsum(x0 * x0 + x1 * x1) * (1.f / 128.f) - mu * mu;
        float inv = rsqrtf(var + 1e-5f);
        latb[t][lane]      = x0;
        latb[t][64 + lane] = x1;
        latn[t][lane]      = (x0 - mu) * inv * ldx<F32>(lg, lane)      + ldx<F32>(lb, lane);
        latn[t][64 + lane] = (x1 - mu) * inv * ldx<F32>(lg, 64 + lane) + ldx<F32>(lb, 64 + lane);
        if (lane < 4) {
            shb [t][lane] = ldx<F32>(esh, (size_t)E * 4 + lane);
            ohib[t][lane] = ldx<F32>(onehot, (size_t)i * 4 + lane);
            ohjb[t][lane] = ldx<F32>(onehot, (size_t)j * 4 + lane);
        }
        if (lane == 0) { cutb[t] = ldx<F32>(cutc, a); aib[t] = a; }
    }
    __syncthreads();

    // ---- Phase 2a: t2[v] = (v_all . sh1) / sqrt(3)  (planar reads) ----
    for (int idx = tid; idx < NE_TILE * 96; idx += 256) {
        int t = idx / 96, v = idx - 96 * t;
        arena[t][192 + v] = (vall[t][v] * shb[t][1] + vall[t][96 + v] * shb[t][2] +
                             vall[t][192 + v] * shb[t][3]) * 0.5773502691896258f;
    }
    // ---- Phase 2b: C1: sWc = s_all @ Wc (K=192,OUT=32); C2: vWd (K=96, OUT=32, 3 comps) ----
    // (no barrier needed: disjoint LDS regions vs 2a)
    {
        const int o = tid & 31, t = tid >> 5;
        float s0 = 0.f, s1 = 0.f, s2 = 0.f, s3 = 0.f;
#pragma unroll 2
        for (int k = 0; k < 192; k += 4) {
            float w0 = ldx<F32>(Wc, (size_t)(k + 0) * 32 + o);
            float w1 = ldx<F32>(Wc, (size_t)(k + 1) * 32 + o);
            float w2 = ldx<F32>(Wc, (size_t)(k + 2) * 32 + o);
            float w3 = ldx<F32>(Wc, (size_t)(k + 3) * 32 + o);
            float4 a = *(const float4*)&arena[t][k];
            s0 += w0 * a.x; s1 += w1 * a.y; s2 += w2 * a.z; s3 += w3 * a.w;
        }
        hidb[t][o] = (s0 + s1) + (s2 + s3);
        float a0 = 0.f, a1 = 0.f, a2 = 0.f;
#pragma unroll 2
        for (int v = 0; v < 96; v += 4) {
            float w0 = ldx<F32>(Wd, (size_t)(v + 0) * 32 + o);
            float w1 = ldx<F32>(Wd, (size_t)(v + 1) * 32 + o);
            float w2 = ldx<F32>(Wd, (size_t)(v + 2) * 32 + o);
            float w3 = ldx<F32>(Wd, (size_t)(v + 3) * 32 + o);
            float4 p0 = *(const float4*)&vall[t][v];
            float4 p1 = *(const float4*)&vall[t][96 + v];
            float4 p2 = *(const float4*)&vall[t][192 + v];
            a0 += w0 * p0.x + w1 * p0.y + w2 * p0.z + w3 * p0.w;
            a1 += w0 * p1.x + w1 * p1.y + w2 * p1.z + w3 * p1.w;
            a2 += w0 * p2.x + w1 * p2.y + w2 * p2.z + w3 * p2.w;
        }
        hidb[t][32 + o] = a0;      // planar: [32 + c*32 + o]
        hidb[t][64 + o] = a1;
        hidb[t][96 + o] = a2;
    }
    __syncthreads();

    // ---- B: o_s = (s_all @ Wa)*sh0 + t2 @ Wb  (sh0 folded: per-edge scalar) ----
    {
        const int o = tid % 96, g = tid / 96;
        if (g < 2) {
            const int t0 = g * 4;
            float acc[4] = {0, 0, 0, 0};
#pragma unroll 2
            for (int k = 0; k < 192; k += 4) {
                float w0 = ldx<F32>(Wa, (size_t)(k + 0) * 96 + o);
                float w1 = ldx<F32>(Wa, (size_t)(k + 1) * 96 + o);
                float w2 = ldx<F32>(Wa, (size_t)(k + 2) * 96 + o);
                float w3 = ldx<F32>(Wa, (size_t)(k + 3) * 96 + o);
#pragma unroll
                for (int e = 0; e < 4; ++e) {
                    float4 a = *(const float4*)&arena[t0 + e][k];
                    acc[e] += w0 * a.x + w1 * a.y + w2 * a.z + w3 * a.w;
                }
            }
#pragma unroll
            for (int e = 0; e < 4; ++e) acc[e] *= shb[t0 + e][0];
#pragma unroll 2
            for (int k = 0; k < 96; k += 4) {
                float w0 = ldx<F32>(Wb, (size_t)(k + 0) * 96 + o);
                float w1 = ldx<F32>(Wb, (size_t)(k + 1) * 96 + o);
                float w2 = ldx<F32>(Wb, (size_t)(k + 2) * 96 + o);
                float w3 = ldx<F32>(Wb, (size_t)(k + 3) * 96 + o);
#pragma unroll
                for (int e = 0; e < 4; ++e) {
                    float4 a = *(const float4*)&arena[t0 + e][192 + k];
                    acc[e] += w0 * a.x + w1 * a.y + w2 * a.z + w3 * a.w;
                }
            }
#pragma unroll
            for (int e = 0; e < 4; ++e) osb[t0 + e][o] = acc[e];
        }
    }
    __syncthreads();

    // ---- elementwise: m_v_pre (planar), m_s_pre, lat_in build, raw edge-feature reload ----
    for (int idx = tid; idx < NE_TILE * 96; idx += 256) {
        int t = idx / 96, r = idx - 96 * t, c = r >> 5, o = r & 31;   // r = c*32+o
        mvpb[t][r] = (hidb[t][o] * shb[t][1 + c] + hidb[t][32 + r] * shb[t][0]) * fsig(osb[t][64 + o]);
    }
    for (int idx = tid; idx < NE_TILE * 64; idx += 256) {
        int t = idx >> 6, o = idx & 63;
        mspb[t][o] = fsilu(osb[t][o]);
    }
    for (int idx = tid; idx < NE_TILE * 232; idx += 256) {
        int t = idx / 232, k = idx - 232 * t;
        float v;
        if (k < 4)        v = ohib[t][k];
        else if (k < 132) v = latn[t][k - 4];
        else if (k < 228) v = osb[t][k - 132];
        else              v = ohjb[t][k - 228];
        arena[t][k] = v;
    }
    for (int idx = tid; idx < NE_TILE * 160; idx += 256) {
        int t = idx / 160, d = idx - 160 * t;
        float val = ldx<F32>(edgef, (size_t)(base + t) * DIMF + d);
        if (d < 64) vall[t][d] = val;
        else { int r = d - 64, v = r / 3, c = r - 3 * v; vall[t][64 + c * 32 + v] = val; }
    }
    __syncthreads();

    // ---- D1: m_s = silu(o_s) @ Wp_s (K=64,OUT=64) ; D2: m_v planar (K=32,OUT=32,3c) ----
    {
        const int o = tid & 63, g = tid >> 6;
        const int t0 = g * 2;
        float acc0 = 0.f, acc1 = 0.f;
#pragma unroll 2
        for (int k = 0; k < 64; k += 4) {
            float w0 = ldx<F32>(Wps, (size_t)(k + 0) * 64 + o);
            float w1 = ldx<F32>(Wps, (size_t)(k + 1) * 64 + o);
            float w2 = ldx<F32>(Wps, (size_t)(k + 2) * 64 + o);
            float w3 = ldx<F32>(Wps, (size_t)(k + 3) * 64 + o);
            float4 a = *(const float4*)&mspb[t0][k];
            float4 b = *(const float4*)&mspb[t0 + 1][k];
            acc0 += w0 * a.x + w1 * a.y + w2 * a.z + w3 * a.w;
            acc1 += w0 * b.x + w1 * b.y + w2 * b.z + w3 * b.w;
        }
        msvb[t0][o]     = acc0;
        msvb[t0 + 1][o] = acc1;
        const int o2 = tid & 31, t = tid >> 5;
        float a0 = 0.f, a1 = 0.f, a2 = 0.f;
#pragma unroll 2
        for (int v = 0; v < 32; v += 4) {
            float w0 = ldx<F32>(Wpv, (size_t)(v + 0) * 32 + o2);
            float w1 = ldx<F32>(Wpv, (size_t)(v + 1) * 32 + o2);
            float w2 = ldx<F32>(Wpv, (size_t)(v + 2) * 32 + o2);
            float w3 = ldx<F32>(Wpv, (size_t)(v + 3) * 32 + o2);
            float4 q0 = *(const float4*)&mvpb[t][v];
            float4 q1 = *(const float4*)&mvpb[t][32 + v];
            float4 q2 = *(const float4*)&mvpb[t][64 + v];
            a0 += w0 * q0.x + w1 * q0.y + w2 * q0.z + w3 * q0.w;
            a1 += w0 * q1.x + w1 * q1.y + w2 * q1.z + w3 * q1.w;
            a2 += w0 * q2.x + w1 * q2.y + w2 * q2.z + w3 * q2.w;
        }
        msvb[t][64 + o2]  = a0;    // planar [64 + c*32 + w]
        msvb[t][96 + o2]  = a1;
        msvb[t][128 + o2] = a2;
    }
    // ---- E: ww = lat @ W_edge (K=128, OUT=96) ----
    {
        const int o = tid % 96, g = tid / 96;
        if (g < 2) {
            const int t0 = g * 4;
            float acc[4] = {0, 0, 0, 0};
#pragma unroll 2
            for (int k = 0; k < 128; k += 4) {
                float w0 = ldx<F32>(Wedge, (size_t)(k + 0) * 96 + o);
                float w1 = ldx<F32>(Wedge, (size_t)(k + 1) * 96 + o);
                float w2 = ldx<F32>(Wedge, (size_t)(k + 2) * 96 + o);
                float w3 = ldx<F32>(Wedge, (size_t)(k + 3) * 96 + o);
#pragma unroll
                for (int e = 0; e < 4; ++e) {
                    float4 a = *(const float4*)&latb[t0 + e][k];
                    acc[e] += w0 * a.x + w1 * a.y + w2 * a.z + w3 * a.w;
                }
            }
#pragma unroll
            for (int e = 0; e < 4; ++e) wwb[t0 + e][o] = acc[e];
        }
    }
    // ---- F1: hid = silu(lat_in @ W_lat1)  (K=232, OUT=256) ----
    {
        const int o = tid;
        float acc[NE_TILE] = {0, 0, 0, 0, 0, 0, 0, 0};
#pragma unroll 2
        for (int k = 0; k < 232; k += 4) {
            float w0 = ldx<F32>(Wl1, (size_t)(k + 0) * 256 + o);
            float w1 = ldx<F32>(Wl1, (size_t)(k + 1) * 256 + o);
            float w2 = ldx<F32>(Wl1, (size_t)(k + 2) * 256 + o);
            float w3 = ldx<F32>(Wl1, (size_t)(k + 3) * 256 + o);
#pragma unroll
            for (int e = 0; e < NE_TILE; ++e) {
                float4 a = *(const float4*)&arena[e][k];
                acc[e] += w0 * a.x + w1 * a.y + w2 * a.z + w3 * a.w;
            }
        }
#pragma unroll
        for (int e = 0; e < NE_TILE; ++e) hidb[e][o] = fsilu(acc[e]);
    }
    __syncthreads();

    // ---- F2: new_lat = (hid @ W_lat2) * cutoff  (K=256, OUT=128) ----
    {
        const int o = tid & 127, g = tid >> 7;
        const int t0 = g * 4;
        float acc[4] = {0, 0, 0, 0};
#pragma unroll 2
        for (int k = 0; k < 256; k += 4) {
            float w0 = ldx<F32>(Wl2, (size_t)(k + 0) * 128 + o);
            float w1 = ldx<F32>(Wl2, (size_t)(k + 1) * 128 + o);
            float w2 = ldx<F32>(Wl2, (size_t)(k + 2) * 128 + o);
            float w3 = ldx<F32>(Wl2, (size_t)(k + 3) * 128 + o);
#pragma unroll
            for (int e = 0; e < 4; ++e) {
                float4 a = *(const float4*)&hidb[t0 + e][k];
                acc[e] += w0 * a.x + w1 * a.y + w2 * a.z + w3 * a.w;
            }
        }
#pragma unroll
        for (int e = 0; e < 4; ++e) {
            int t = t0 + e;
            stx<F32>(out_lat, (size_t)aib[t] * LATD + o, acc[e] * cutb[t]);
        }
    }
    // ---- G1: e_s + r_s @ Wres_s  (K=64, OUT=64) ----
    {
        const int o = tid & 63, g = tid >> 6;
        const int t0 = g * 2;
        float acc0 = 0.f, acc1 = 0.f;
#pragma unroll 2
        for (int k = 0; k < 64; k += 4) {
            float w0 = ldx<F32>(Wrs, (size_t)(k + 0) * 64 + o);
            float w1 = ldx<F32>(Wrs, (size_t)(k + 1) * 64 + o);
            float w2 = ldx<F32>(Wrs, (size_t)(k + 2) * 64 + o);
            float w3 = ldx<F32>(Wrs, (size_t)(k + 3) * 64 + o);
            float4 a = *(const float4*)&vall[t0][k];
            float4 b = *(const float4*)&vall[t0 + 1][k];
            acc0 += w0 * a.x + w1 * a.y + w2 * a.z + w3 * a.w;
            acc1 += w0 * b.x + w1 * b.y + w2 * b.z + w3 * b.w;
        }
        stx<F32>(out_edge, (size_t)(base + t0)     * DIMF + o, msvb[t0][o]     * wwb[t0][o]     + acc0);
        stx<F32>(out_edge, (size_t)(base + t0 + 1) * DIMF + o, msvb[t0 + 1][o] * wwb[t0 + 1][o] + acc1);
        // ---- G2: e_v + r_v @ Wres_v  (K=32, OUT=32, planar comps) ----
        const int o2 = tid & 31, t = tid >> 5;
        float a0 = 0.f, a1 = 0.f, a2 = 0.f;
#pragma unroll 2
        for (int v = 0; v < 32; v += 4) {
            float w0 = ldx<F32>(Wrv, (size_t)(v + 0) * 32 + o2);
            float w1 = ldx<F32>(Wrv, (size_t)(v + 1) * 32 + o2);
            float w2 = ldx<F32>(Wrv, (size_t)(v + 2) * 32 + o2);
            float w3 = ldx<F32>(Wrv, (size_t)(v + 3) * 32 + o2);
            float4 q0 = *(const float4*)&vall[t][64 + v];
            float4 q1 = *(const float4*)&vall[t][96 + v];
            float4 q2 = *(const float4*)&vall[t][128 + v];
            a0 += w0 * q0.x + w1 * q0.y + w2 * q0.z + w3 * q0.w;
            a1 += w0 * q1.x + w1 * q1.y + w2 * q1.z + w3 * q1.w;
            a2 += w0 * q2.x + w1 * q2.y + w2 * q2.z + w3 * q2.w;
        }
        float wv = wwb[t][64 + o2];
        size_t eb = (size_t)(base + t) * DIMF + 64;
        stx<F32>(out_edge, eb + 3 * o2    , msvb[t][64 + o2]  * wv + a0);
        stx<F32>(out_edge, eb + 3 * o2 + 1, msvb[t][96 + o2]  * wv + a1);
        stx<F32>(out_edge, eb + 3 * o2 + 2, msvb[t][128 + o2] * wv + a2);
    }
}

extern "C" void kernel_launch(void* const* d_in, const int* in_sizes, int n_in,
                              void* d_out, int out_size, void* d_ws, size_t ws_size,
                              hipStream_t stream) {
    const void* latents = d_in[0];
    const void* nodef   = d_in[1];
    const void* onehot  = d_in[2];
    const void* edgef   = d_in[3];
    const void* esh     = d_in[4];
    const int*  eidx    = (const int*)d_in[5];
    const void* cutc    = d_in[6];
    const int*  act     = (const int*)d_in[7];

    int* flag = (int*)d_ws;
    detect_kernel<<<1, 256, 0, stream>>>((const u16*)d_in[1], flag);

    const size_t EDGE_ELEMS = (size_t)N_ACT_K * DIMF;  // 32,000,000
    void* out_lat_b = (void*)((u16*)d_out + EDGE_ELEMS);
    void* out_lat_f = (void*)((float*)d_out + EDGE_ELEMS);

    // Copy latents -> latents_out (active rows overwritten by edge_kernel afterwards).
    copy_lat_kernel<0><<<(N_EDGES_K * LATD / 8) / 256, 256, 0, stream>>>(
        flag, (const uint4*)latents, (uint4*)out_lat_b, N_EDGES_K * LATD / 8);
    copy_lat_kernel<1><<<(N_EDGES_K * LATD / 4) / 256, 256, 0, stream>>>(
        flag, (const uint4*)latents, (uint4*)out_lat_f, N_EDGES_K * LATD / 4);

    edge_kernel<0><<<N_ACT_K / NE_TILE, 256, 0, stream>>>(
        flag, latents, nodef, onehot, edgef, esh, eidx, cutc, act,
        d_in[8], d_in[9], d_in[10], d_in[11], d_in[12], d_in[13], d_in[14], d_in[15],
        d_in[16], d_in[17], d_in[18], d_in[19], d_in[20], d_in[21], d_in[22], d_in[23],
        d_in[24], d_in[25], d_in[26],
        d_out, out_lat_b);
    edge_kernel<1><<<N_ACT_K / NE_TILE, 256, 0, stream>>>(
        flag, latents, nodef, onehot, edgef, esh, eidx, cutc, act,
        d_in[8], d_in[9], d_in[10], d_in[11], d_in[12], d_in[13], d_in[14], d_in[15],
        d_in[16], d_in[17], d_in[18], d_in[19], d_in[20], d_in[21], d_in[22], d_in[23],
        d_in[24], d_in[25], d_in[26],
        d_out, out_lat_f);
}

// Round 2
// 2493.536 us; speedup vs baseline: 1.0571x; 1.0571x over previous
//
#include <hip/hip_runtime.h>
#include <stdint.h>

// Problem constants
#define NSC 64
#define NVC 32
#define DIMF 160
#define LATD 128
#define HIDD 256
#define N_EDGES_K 300000
#define N_ACT_K 200000
#define NE_TILE 8

typedef unsigned short u16;

__device__ __forceinline__ float b2f(u16 x) {
    union { unsigned int u; float f; } v; v.u = ((unsigned int)x) << 16; return v.f;
}
__device__ __forceinline__ u16 f2b(float f) {
    union { unsigned int u; float f; } v; v.f = f;
    return (u16)((v.u + 0x7fffu + ((v.u >> 16) & 1u)) >> 16);
}

// F32=1: buffer is float32.  F32=0: buffer is bf16 (u16).
template<int F32>
__device__ __forceinline__ float ldx(const void* p, size_t i) {
    if (F32) return ((const float*)p)[i];
    return b2f(((const u16*)p)[i]);
}
template<int F32>
__device__ __forceinline__ void stx(void* p, size_t i, float v) {
    if (!(fabsf(v) < 1e30f)) v = 12345.0f;  // NaN/inf -> visible finite sentinel
    if (F32) ((float*)p)[i] = v;
    else     ((u16*)p)[i] = f2b(v);
}

__device__ __forceinline__ float wsum(float v) {
#pragma unroll
    for (int m = 32; m > 0; m >>= 1) v += __shfl_xor(v, m, 64);
    return v;
}
__device__ __forceinline__ float fsig(float x)  { return 1.f / (1.f + __expf(-x)); }
__device__ __forceinline__ float fsilu(float x) { return x / (1.f + __expf(-x)); }

// Normalize one DIM=160 row; vector part written COMPONENT-PLANAR dvp[c*96+vbase+v].
template<int F32>
__device__ __forceinline__ void norm_row(const void* __restrict__ row, size_t off,
                                         const void* __restrict__ gs,
                                         const void* __restrict__ bs,
                                         const void* __restrict__ gv,
                                         float* ds, float* dvp, int vbase, int lane) {
    float s  = ldx<F32>(row, off + lane);
    float va = ldx<F32>(row, off + 64 + lane);
    float vb = (lane < 32) ? ldx<F32>(row, off + 128 + lane) : 0.f;
    float mu  = wsum(s) * (1.f / 64.f);
    float var = wsum(s * s) * (1.f / 64.f) - mu * mu;
    float n2  = wsum(va * va + vb * vb);
    float invs = rsqrtf(var + 1e-5f);
    float invv = rsqrtf(n2 * (1.f / 32.f) + 1e-5f);
    ds[lane] = (s - mu) * invs * ldx<F32>(gs, lane) + ldx<F32>(bs, lane);
    int v1 = lane / 3, c1 = lane - 3 * v1;
    dvp[c1 * 96 + vbase + v1] = va * invv * ldx<F32>(gv, v1);
    if (lane < 32) {
        int p = 64 + lane;
        int v2 = p / 3, c2 = p - 3 * v2;
        dvp[c2 * 96 + vbase + v2] = vb * invv * ldx<F32>(gv, v2);
    }
}

// Detect input dtype from node_features bit patterns.
__global__ void detect_kernel(const u16* __restrict__ probe, int* __restrict__ flag) {
    __shared__ int cnt;
    if (threadIdx.x == 0) cnt = 0;
    __syncthreads();
    u16 x = probe[threadIdx.x];
    int e = (x >> 7) & 0xFF;
    int sane = ((x & 0x7FFF) == 0) || (e >= 96 && e <= 143);
    atomicAdd(&cnt, sane);
    __syncthreads();
    if (threadIdx.x == 0) *flag = (cnt >= 240) ? 0 : 1;  // 0 = bf16, 1 = f32
}

template<int F32>
__global__ void copy_lat_kernel(const int* __restrict__ flag,
                                const uint4* __restrict__ in, uint4* __restrict__ out, int n) {
    if (*flag != F32) return;
    int i = blockIdx.x * blockDim.x + threadIdx.x;
    if (i < n) out[i] = in[i];
}

// ---- weight pre-conversion to f32 workspace ----
// segments: Wa Wb Wc Wd Wps Wpv Wedge Wl1 Wl2 Wrs Wrv lg lb
#define NSEG 13
__device__ __constant__ const int g_seg_sz[NSEG]  = {18432,9216,6144,3072,4096,1024,12288,59392,32768,4096,1024,128,128};
__device__ __constant__ const int g_seg_off[NSEG] = {0,18432,27648,33792,36864,40960,41984,54272,113664,146432,150528,151552,151680};
#define WS_FLOATS 151808

template<int F32>
__global__ void conv_kernel(const int* __restrict__ flag, float* __restrict__ dst,
                            const void* p0, const void* p1, const void* p2, const void* p3,
                            const void* p4, const void* p5, const void* p6, const void* p7,
                            const void* p8, const void* p9, const void* p10, const void* p11,
                            const void* p12) {
    if (*flag != F32) return;
    int s = blockIdx.y;
    int i = blockIdx.x * blockDim.x + threadIdx.x;
    const void* p;
    switch (s) {
        case 0: p = p0; break;  case 1: p = p1; break;  case 2: p = p2; break;
        case 3: p = p3; break;  case 4: p = p4; break;  case 5: p = p5; break;
        case 6: p = p6; break;  case 7: p = p7; break;  case 8: p = p8; break;
        case 9: p = p9; break;  case 10: p = p10; break; case 11: p = p11; break;
        default: p = p12; break;
    }
    if (i < g_seg_sz[s]) dst[g_seg_off[s] + i] = ldx<F32>(p, i);
}

// WCONV=1: weights/lg/lb are f32 (pre-converted in ws). WCONV=0: original dtype (F32).
template<int F32, int WCONV>
__global__ __launch_bounds__(256, 4)
void edge_kernel(const int* __restrict__ flag,
                 const void* __restrict__ latents,
                 const void* __restrict__ nodef,
                 const void* __restrict__ onehot,
                 const void* __restrict__ edgef,
                 const void* __restrict__ esh,
                 const int* __restrict__ eidx,
                 const void* __restrict__ cutc,
                 const int* __restrict__ act,
                 const void* __restrict__ n_gs, const void* __restrict__ n_bs, const void* __restrict__ n_gv,
                 const void* __restrict__ e_gs, const void* __restrict__ e_bs, const void* __restrict__ e_gv,
                 const void* __restrict__ LG, const void* __restrict__ LB,
                 const void* __restrict__ Wa, const void* __restrict__ Wb,
                 const void* __restrict__ Wc, const void* __restrict__ Wd,
                 const void* __restrict__ Wps, const void* __restrict__ Wpv,
                 const void* __restrict__ Wedge, const void* __restrict__ Wl1,
                 const void* __restrict__ Wl2, const void* __restrict__ Wrs,
                 const void* __restrict__ Wrv,
                 void* __restrict__ out_edge, void* __restrict__ out_lat)
{
    if (*flag != F32) return;
    constexpr int WF = WCONV ? 1 : F32;   // weight-load dtype
#define WLD(P, I) ldx<WF>(P, (I))

    // ---------------- LDS overlays (36.4 KB total -> 4 blocks/CU) ----------------
    // arena: early = s_all(0..191)+t2(192..287); late(F1 onward) = hid(0..255)
    __shared__ float arena[NE_TILE][288];
    // vall: early = v_all planar [c*96+v]; late(elementwise onward) = lat_in(0..231)
    __shared__ float vall[NE_TILE][288];
    __shared__ float latb[NE_TILE][128];   // raw latents (live until E)
    __shared__ float oswb[NE_TILE][96];    // early: o_s (B->elementwise); late: ww (E->G)
    __shared__ float msvb[NE_TILE][160];   // early: sWc(0..31)+vWd planar(32..127); late: m_s(0..63)+m_v planar(64..159)
    __shared__ float mspb[NE_TILE][64];
    __shared__ float mvpb[NE_TILE][96];    // planar [c*32+o]
    __shared__ float shb [NE_TILE][4];
    __shared__ float ohib[NE_TILE][4];
    __shared__ float ohjb[NE_TILE][4];
    __shared__ float cutb[NE_TILE];
    __shared__ float muiv[NE_TILE][2];     // latent LN mu, inv
    __shared__ int   aib [NE_TILE];

    const int tid  = threadIdx.x;
    const int wid  = tid >> 6;
    const int lane = tid & 63;
    const int base = blockIdx.x * NE_TILE;

    // ---- Phase A: load + normalize (one wave per edge) ----
    for (int t = wid; t < NE_TILE; t += 4) {
        const int E = base + t;
        const int a = act[E];
        const int i = eidx[a];
        const int j = eidx[N_EDGES_K + a];
        norm_row<F32>(nodef, (size_t)i * DIMF, n_gs, n_bs, n_gv, &arena[t][0],   &vall[t][0], 0,  lane);
        norm_row<F32>(edgef, (size_t)E * DIMF, e_gs, e_bs, e_gv, &arena[t][64],  &vall[t][0], 32, lane);
        norm_row<F32>(nodef, (size_t)j * DIMF, n_gs, n_bs, n_gv, &arena[t][128], &vall[t][0], 64, lane);
        float x0 = ldx<F32>(latents, (size_t)a * LATD + lane);
        float x1 = ldx<F32>(latents, (size_t)a * LATD + 64 + lane);
        float mu  = wsum(x0 + x1) * (1.f / 128.f);
        float var = wsum(x0 * x0 + x1 * x1) * (1.f / 128.f) - mu * mu;
        float inv = rsqrtf(var + 1e-5f);
        latb[t][lane]      = x0;
        latb[t][64 + lane] = x1;
        if (lane < 4) {
            shb [t][lane] = ldx<F32>(esh, (size_t)E * 4 + lane);
            ohib[t][lane] = ldx<F32>(onehot, (size_t)i * 4 + lane);
            ohjb[t][lane] = ldx<F32>(onehot, (size_t)j * 4 + lane);
        }
        if (lane == 0) {
            cutb[t] = ldx<F32>(cutc, a); aib[t] = a;
            muiv[t][0] = mu; muiv[t][1] = inv;
        }
    }
    __syncthreads();

    // ---- Phase 2a: t2[v] = (v_all . sh1)/sqrt(3) -> arena[192..287] ----
    for (int idx = tid; idx < NE_TILE * 96; idx += 256) {
        int t = idx / 96, v = idx - 96 * t;
        arena[t][192 + v] = (vall[t][v] * shb[t][1] + vall[t][96 + v] * shb[t][2] +
                             vall[t][192 + v] * shb[t][3]) * 0.5773502691896258f;
    }
    // ---- Phase 2b: C1 sWc (K=192,OUT=32); C2 vWd planar (K=96,OUT=32,3c) -> msvb early ----
    {
        const int o = tid & 31, t = tid >> 5;
        float s0 = 0.f, s1 = 0.f, s2 = 0.f, s3 = 0.f;
#pragma unroll 2
        for (int k = 0; k < 192; k += 4) {
            float w0 = WLD(Wc, (k + 0) * 32 + o);
            float w1 = WLD(Wc, (k + 1) * 32 + o);
            float w2 = WLD(Wc, (k + 2) * 32 + o);
            float w3 = WLD(Wc, (k + 3) * 32 + o);
            float4 a = *(const float4*)&arena[t][k];
            s0 += w0 * a.x; s1 += w1 * a.y; s2 += w2 * a.z; s3 += w3 * a.w;
        }
        msvb[t][o] = (s0 + s1) + (s2 + s3);
        float a0 = 0.f, a1 = 0.f, a2 = 0.f;
#pragma unroll 2
        for (int v = 0; v < 96; v += 4) {
            float w0 = WLD(Wd, (v + 0) * 32 + o);
            float w1 = WLD(Wd, (v + 1) * 32 + o);
            float w2 = WLD(Wd, (v + 2) * 32 + o);
            float w3 = WLD(Wd, (v + 3) * 32 + o);
            float4 p0 = *(const float4*)&vall[t][v];
            float4 p1 = *(const float4*)&vall[t][96 + v];
            float4 p2 = *(const float4*)&vall[t][192 + v];
            a0 += w0 * p0.x + w1 * p0.y + w2 * p0.z + w3 * p0.w;
            a1 += w0 * p1.x + w1 * p1.y + w2 * p1.z + w3 * p1.w;
            a2 += w0 * p2.x + w1 * p2.y + w2 * p2.z + w3 * p2.w;
        }
        msvb[t][32 + o] = a0;    // vWd planar [32 + c*32 + o]
        msvb[t][64 + o] = a1;
        msvb[t][96 + o] = a2;
    }
    __syncthreads();

    // ---- B: o_s = (s_all @ Wa)*sh0 + t2 @ Wb  (sh0 folded) -> oswb ----
    {
        const int o = tid % 96, g = tid / 96;
        if (g < 2) {
            const int t0 = g * 4;
            float acc[4] = {0, 0, 0, 0};
#pragma unroll 2
            for (int k = 0; k < 192; k += 4) {
                float w0 = WLD(Wa, (k + 0) * 96 + o);
                float w1 = WLD(Wa, (k + 1) * 96 + o);
                float w2 = WLD(Wa, (k + 2) * 96 + o);
                float w3 = WLD(Wa, (k + 3) * 96 + o);
#pragma unroll
                for (int e = 0; e < 4; ++e) {
                    float4 a = *(const float4*)&arena[t0 + e][k];
                    acc[e] += w0 * a.x + w1 * a.y + w2 * a.z + w3 * a.w;
                }
            }
#pragma unroll
            for (int e = 0; e < 4; ++e) acc[e] *= shb[t0 + e][0];
#pragma unroll 2
            for (int k = 0; k < 96; k += 4) {
                float w0 = WLD(Wb, (k + 0) * 96 + o);
                float w1 = WLD(Wb, (k + 1) * 96 + o);
                float w2 = WLD(Wb, (k + 2) * 96 + o);
                float w3 = WLD(Wb, (k + 3) * 96 + o);
#pragma unroll
                for (int e = 0; e < 4; ++e) {
                    float4 a = *(const float4*)&arena[t0 + e][192 + k];
                    acc[e] += w0 * a.x + w1 * a.y + w2 * a.z + w3 * a.w;
                }
            }
#pragma unroll
            for (int e = 0; e < 4; ++e) oswb[t0 + e][o] = acc[e];
        }
    }
    __syncthreads();

    // ---- elementwise: m_v_pre, m_s_pre, lat_in (into vall, LN recomputed on the fly) ----
    for (int idx = tid; idx < NE_TILE * 96; idx += 256) {
        int t = idx / 96, r = idx - 96 * t, c = r >> 5, o = r & 31;   // r = c*32+o
        mvpb[t][r] = (msvb[t][o] * shb[t][1 + c] + msvb[t][32 + r] * shb[t][0]) * fsig(oswb[t][64 + o]);
    }
    for (int idx = tid; idx < NE_TILE * 64; idx += 256) {
        int t = idx >> 6, o = idx & 63;
        mspb[t][o] = fsilu(oswb[t][o]);
    }
    for (int idx = tid; idx < NE_TILE * 232; idx += 256) {
        int t = idx / 232, k = idx - 232 * t;
        float v;
        if (k < 4)        v = ohib[t][k];
        else if (k < 132) {
            int j = k - 4;
            v = (latb[t][j] - muiv[t][0]) * muiv[t][1] * WLD(LG, j) + WLD(LB, j);
        }
        else if (k < 228) v = oswb[t][k - 132];
        else              v = ohjb[t][k - 228];
        vall[t][k] = v;
    }
    __syncthreads();

    // ---- D1: m_s = silu(o_s) @ Wp_s ; D2: m_v planar -> msvb late ----
    {
        const int o = tid & 63, g = tid >> 6;
        const int t0 = g * 2;
        float acc0 = 0.f, acc1 = 0.f;
#pragma unroll 2
        for (int k = 0; k < 64; k += 4) {
            float w0 = WLD(Wps, (k + 0) * 64 + o);
            float w1 = WLD(Wps, (k + 1) * 64 + o);
            float w2 = WLD(Wps, (k + 2) * 64 + o);
            float w3 = WLD(Wps, (k + 3) * 64 + o);
            float4 a = *(const float4*)&mspb[t0][k];
            float4 b = *(const float4*)&mspb[t0 + 1][k];
            acc0 += w0 * a.x + w1 * a.y + w2 * a.z + w3 * a.w;
            acc1 += w0 * b.x + w1 * b.y + w2 * b.z + w3 * b.w;
        }
        msvb[t0][o]     = acc0;
        msvb[t0 + 1][o] = acc1;
        const int o2 = tid & 31, t = tid >> 5;
        float a0 = 0.f, a1 = 0.f, a2 = 0.f;
#pragma unroll 2
        for (int v = 0; v < 32; v += 4) {
            float w0 = WLD(Wpv, (v + 0) * 32 + o2);
            float w1 = WLD(Wpv, (v + 1) * 32 + o2);
            float w2 = WLD(Wpv, (v + 2) * 32 + o2);
            float w3 = WLD(Wpv, (v + 3) * 32 + o2);
            float4 q0 = *(const float4*)&mvpb[t][v];
            float4 q1 = *(const float4*)&mvpb[t][32 + v];
            float4 q2 = *(const float4*)&mvpb[t][64 + v];
            a0 += w0 * q0.x + w1 * q0.y + w2 * q0.z + w3 * q0.w;
            a1 += w0 * q1.x + w1 * q1.y + w2 * q1.z + w3 * q1.w;
            a2 += w0 * q2.x + w1 * q2.y + w2 * q2.z + w3 * q2.w;
        }
        msvb[t][64 + o2]  = a0;
        msvb[t][96 + o2]  = a1;
        msvb[t][128 + o2] = a2;
    }
    // ---- E: ww = lat @ W_edge (K=128,OUT=96) -> oswb (o_s dead) ----
    {
        const int o = tid % 96, g = tid / 96;
        if (g < 2) {
            const int t0 = g * 4;
            float acc[4] = {0, 0, 0, 0};
#pragma unroll 2
            for (int k = 0; k < 128; k += 4) {
                float w0 = WLD(Wedge, (k + 0) * 96 + o);
                float w1 = WLD(Wedge, (k + 1) * 96 + o);
                float w2 = WLD(Wedge, (k + 2) * 96 + o);
                float w3 = WLD(Wedge, (k + 3) * 96 + o);
#pragma unroll
                for (int e = 0; e < 4; ++e) {
                    float4 a = *(const float4*)&latb[t0 + e][k];
                    acc[e] += w0 * a.x + w1 * a.y + w2 * a.z + w3 * a.w;
                }
            }
#pragma unroll
            for (int e = 0; e < 4; ++e) oswb[t0 + e][o] = acc[e];
        }
    }
    // ---- F1: hid = silu(lat_in @ W_lat1) (K=232,OUT=256) -> arena (s_all dead) ----
    {
        const int o = tid;
        float acc[NE_TILE] = {0, 0, 0, 0, 0, 0, 0, 0};
#pragma unroll 2
        for (int k = 0; k < 232; k += 4) {
            float w0 = WLD(Wl1, (k + 0) * 256 + o);
            float w1 = WLD(Wl1, (k + 1) * 256 + o);
            float w2 = WLD(Wl1, (k + 2) * 256 + o);
            float w3 = WLD(Wl1, (k + 3) * 256 + o);
#pragma unroll
            for (int e = 0; e < NE_TILE; ++e) {
                float4 a = *(const float4*)&vall[e][k];
                acc[e] += w0 * a.x + w1 * a.y + w2 * a.z + w3 * a.w;
            }
        }
#pragma unroll
        for (int e = 0; e < NE_TILE; ++e) arena[e][o] = fsilu(acc[e]);
    }
    __syncthreads();

    // ---- F2: new_lat = (hid @ W_lat2) * cutoff ----
    {
        const int o = tid & 127, g = tid >> 7;
        const int t0 = g * 4;
        float acc[4] = {0, 0, 0, 0};
#pragma unroll 2
        for (int k = 0; k < 256; k += 4) {
            float w0 = WLD(Wl2, (k + 0) * 128 + o);
            float w1 = WLD(Wl2, (k + 1) * 128 + o);
            float w2 = WLD(Wl2, (k + 2) * 128 + o);
            float w3 = WLD(Wl2, (k + 3) * 128 + o);
#pragma unroll
            for (int e = 0; e < 4; ++e) {
                float4 a = *(const float4*)&arena[t0 + e][k];
                acc[e] += w0 * a.x + w1 * a.y + w2 * a.z + w3 * a.w;
            }
        }
#pragma unroll
        for (int e = 0; e < 4; ++e) {
            int t = t0 + e;
            stx<F32>(out_lat, (size_t)aib[t] * LATD + o, acc[e] * cutb[t]);
        }
    }
    // ---- G1: e_s + r_s @ Wres_s (raw edge read from global: L2-hot, wave-uniform addr) ----
    {
        const int o = tid & 63, g = tid >> 6;
        const int t0 = g * 2;
        const size_t b0 = (size_t)(base + t0) * DIMF;
        const size_t b1 = b0 + DIMF;
        float acc0 = 0.f, acc1 = 0.f;
#pragma unroll 2
        for (int k = 0; k < 64; k += 4) {
            float w0 = WLD(Wrs, (k + 0) * 64 + o);
            float w1 = WLD(Wrs, (k + 1) * 64 + o);
            float w2 = WLD(Wrs, (k + 2) * 64 + o);
            float w3 = WLD(Wrs, (k + 3) * 64 + o);
            acc0 += w0 * ldx<F32>(edgef, b0 + k)     + w1 * ldx<F32>(edgef, b0 + k + 1)
                  + w2 * ldx<F32>(edgef, b0 + k + 2) + w3 * ldx<F32>(edgef, b0 + k + 3);
            acc1 += w0 * ldx<F32>(edgef, b1 + k)     + w1 * ldx<F32>(edgef, b1 + k + 1)
                  + w2 * ldx<F32>(edgef, b1 + k + 2) + w3 * ldx<F32>(edgef, b1 + k + 3);
        }
        stx<F32>(out_edge, b0 + o, msvb[t0][o]     * oswb[t0][o]     + acc0);
        stx<F32>(out_edge, b1 + o, msvb[t0 + 1][o] * oswb[t0 + 1][o] + acc1);
        // ---- G2: e_v + r_v @ Wres_v ----
        const int o2 = tid & 31, t = tid >> 5;
        const size_t eb = (size_t)(base + t) * DIMF + 64;
        float a0 = 0.f, a1 = 0.f, a2 = 0.f;
#pragma unroll 4
        for (int v = 0; v < 32; ++v) {
            float w = WLD(Wrv, v * 32 + o2);
            a0 += w * ldx<F32>(edgef, eb + 3 * v);
            a1 += w * ldx<F32>(edgef, eb + 3 * v + 1);
            a2 += w * ldx<F32>(edgef, eb + 3 * v + 2);
        }
        float wv = oswb[t][64 + o2];
        stx<F32>(out_edge, eb + 3 * o2    , msvb[t][64 + o2]  * wv + a0);
        stx<F32>(out_edge, eb + 3 * o2 + 1, msvb[t][96 + o2]  * wv + a1);
        stx<F32>(out_edge, eb + 3 * o2 + 2, msvb[t][128 + o2] * wv + a2);
    }
#undef WLD
}

extern "C" void kernel_launch(void* const* d_in, const int* in_sizes, int n_in,
                              void* d_out, int out_size, void* d_ws, size_t ws_size,
                              hipStream_t stream) {
    const void* latents = d_in[0];
    const void* nodef   = d_in[1];
    const void* onehot  = d_in[2];
    const void* edgef   = d_in[3];
    const void* esh     = d_in[4];
    const int*  eidx    = (const int*)d_in[5];
    const void* cutc    = d_in[6];
    const int*  act     = (const int*)d_in[7];

    int* flag = (int*)d_ws;
    detect_kernel<<<1, 256, 0, stream>>>((const u16*)d_in[1], flag);

    const size_t EDGE_ELEMS = (size_t)N_ACT_K * DIMF;  // 32,000,000
    void* out_lat_b = (void*)((u16*)d_out + EDGE_ELEMS);
    void* out_lat_f = (void*)((float*)d_out + EDGE_ELEMS);

    copy_lat_kernel<0><<<(N_EDGES_K * LATD / 8) / 256, 256, 0, stream>>>(
        flag, (const uint4*)latents, (uint4*)out_lat_b, N_EDGES_K * LATD / 8);
    copy_lat_kernel<1><<<(N_EDGES_K * LATD / 4) / 256, 256, 0, stream>>>(
        flag, (const uint4*)latents, (uint4*)out_lat_f, N_EDGES_K * LATD / 4);

    const size_t WS_NEED = 256 + (size_t)WS_FLOATS * 4;
    const bool wsok = ws_size >= WS_NEED;

    if (wsok) {
        float* wsW = (float*)((char*)d_ws + 256);
        dim3 cg((59392 + 255) / 256, NSEG);
        conv_kernel<0><<<cg, 256, 0, stream>>>(flag, wsW,
            d_in[16], d_in[17], d_in[18], d_in[19], d_in[20], d_in[21], d_in[22],
            d_in[23], d_in[24], d_in[25], d_in[26], d_in[14], d_in[15]);
        conv_kernel<1><<<cg, 256, 0, stream>>>(flag, wsW,
            d_in[16], d_in[17], d_in[18], d_in[19], d_in[20], d_in[21], d_in[22],
            d_in[23], d_in[24], d_in[25], d_in[26], d_in[14], d_in[15]);
        const float* Wa    = wsW + 0;
        const float* Wb    = wsW + 18432;
        const float* Wc    = wsW + 27648;
        const float* Wd    = wsW + 33792;
        const float* Wps   = wsW + 36864;
        const float* Wpv   = wsW + 40960;
        const float* Wedge = wsW + 41984;
        const float* Wl1   = wsW + 54272;
        const float* Wl2   = wsW + 113664;
        const float* Wrs   = wsW + 146432;
        const float* Wrv   = wsW + 150528;
        const float* lg    = wsW + 151552;
        const float* lb    = wsW + 151680;
        edge_kernel<0, 1><<<N_ACT_K / NE_TILE, 256, 0, stream>>>(
            flag, latents, nodef, onehot, edgef, esh, eidx, cutc, act,
            d_in[8], d_in[9], d_in[10], d_in[11], d_in[12], d_in[13], lg, lb,
            Wa, Wb, Wc, Wd, Wps, Wpv, Wedge, Wl1, Wl2, Wrs, Wrv,
            d_out, out_lat_b);
        edge_kernel<1, 1><<<N_ACT_K / NE_TILE, 256, 0, stream>>>(
            flag, latents, nodef, onehot, edgef, esh, eidx, cutc, act,
            d_in[8], d_in[9], d_in[10], d_in[11], d_in[12], d_in[13], lg, lb,
            Wa, Wb, Wc, Wd, Wps, Wpv, Wedge, Wl1, Wl2, Wrs, Wrv,
            d_out, out_lat_f);
    } else {
        edge_kernel<0, 0><<<N_ACT_K / NE_TILE, 256, 0, stream>>>(
            flag, latents, nodef, onehot, edgef, esh, eidx, cutc, act,
            d_in[8], d_in[9], d_in[10], d_in[11], d_in[12], d_in[13], d_in[14], d_in[15],
            d_in[16], d_in[17], d_in[18], d_in[19], d_in[20], d_in[21], d_in[22],
            d_in[23], d_in[24], d_in[25], d_in[26],
            d_out, out_lat_b);
        edge_kernel<1, 0><<<N_ACT_K / NE_TILE, 256, 0, stream>>>(
            flag, latents, nodef, onehot, edgef, esh, eidx, cutc, act,
            d_in[8], d_in[9], d_in[10], d_in[11], d_in[12], d_in[13], d_in[14], d_in[15],
            d_in[16], d_in[17], d_in[18], d_in[19], d_in[20], d_in[21], d_in[22],
            d_in[23], d_in[24], d_in[25], d_in[26],
            d_out, out_lat_f);
    }
}